// Round 5
// baseline (1197.075 us; speedup 1.0000x reference)
//
#include <hip/hip_runtime.h>
#include <cstdint>
#include <cstddef>

using short8   = __attribute__((ext_vector_type(8))) short;
using f32x4    = __attribute__((ext_vector_type(4))) float;
using ushort4v = __attribute__((ext_vector_type(4))) unsigned short;

#define B_    32
#define N_    577
#define C_    768
#define H_    12
#define HD_   64
#define NPAD  640
#define MROWS 18464   // B*N
#define MPAD  18560   // 145*128
#define NQKV  2304    // 3*C
#define SCALE 0.125f
#define OUT0_ELTS 14180352   // B*N*C

static __device__ __forceinline__ unsigned short f2bf(float f) {
  union { float f; unsigned int u; } v; v.f = f;
  return (unsigned short)((v.u + 0x7FFFu + ((v.u >> 16) & 1u)) >> 16);
}

static __device__ __forceinline__ void gload_lds16(const unsigned short* g, unsigned short* l) {
  __builtin_amdgcn_global_load_lds(
      (const __attribute__((address_space(1))) unsigned int*)g,
      (__attribute__((address_space(3))) unsigned int*)l, 16, 0, 0);
}

// ---------------- f32 -> bf16 convert ----------------
__global__ __launch_bounds__(256) void cvt_f32_bf16(const float* __restrict__ src,
                                                    unsigned short* __restrict__ dst, int n4) {
  int i = blockIdx.x * 256 + threadIdx.x;
  if (i >= n4) return;
  f32x4 v = ((const f32x4*)src)[i];
  ushort4v o;
  o.x = f2bf(v.x); o.y = f2bf(v.y); o.z = f2bf(v.z); o.w = f2bf(v.w);
  ((ushort4v*)dst)[i] = o;
}

// ---------------- QKV GEMM: C[m,n] = sum_k xb[m,k]*Wqkv[n,k], scatter to q/k/vT ----------------
__global__ __launch_bounds__(256) void gemm_qkv(
    const unsigned short* __restrict__ A,    // xb [MPAD][768]
    const unsigned short* __restrict__ Bw,   // wqkvb [2304][768]
    unsigned short* __restrict__ qb,         // [B*H][640][64]
    unsigned short* __restrict__ kbuf,       // [B*H][640][64]
    unsigned short* __restrict__ vtb)        // [B*H][64][640]
{
  __shared__ unsigned short As[128 * 64];
  __shared__ unsigned short Bs[128 * 64];
  const int mt = blockIdx.x, nt = blockIdx.y;
  const int tid = threadIdx.x;
  const int wave = tid >> 6, lane = tid & 63;
  const int wm = wave >> 1, wn = wave & 1;
  const int lq = lane & 15, grp = lane >> 4;

  f32x4 acc[4][4] = {};

  const int arowbase = mt * 128;
  const int browbase = nt * 128;
  const int srow = wave * 8 + (lane >> 3);
  const int scol = (lane & 7) * 8;

  for (int kblk = 0; kblk < 12; ++kblk) {
    const int koff = kblk * 64;
#pragma unroll
    for (int i = 0; i < 4; ++i) {
      gload_lds16(A  + (size_t)(arowbase + i * 32 + srow) * 768 + koff + scol,
                  &As[(i * 32 + wave * 8) * 64]);
      gload_lds16(Bw + (size_t)(browbase + i * 32 + srow) * 768 + koff + scol,
                  &Bs[(i * 32 + wave * 8) * 64]);
    }
    __syncthreads();
#pragma unroll
    for (int ks = 0; ks < 2; ++ks) {
      short8 af[4], bf[4];
#pragma unroll
      for (int mi = 0; mi < 4; ++mi)
        af[mi] = *(const short8*)&As[(wm * 64 + mi * 16 + lq) * 64 + ks * 32 + grp * 8];
#pragma unroll
      for (int ni = 0; ni < 4; ++ni)
        bf[ni] = *(const short8*)&Bs[(wn * 64 + ni * 16 + lq) * 64 + ks * 32 + grp * 8];
#pragma unroll
      for (int mi = 0; mi < 4; ++mi)
#pragma unroll
        for (int ni = 0; ni < 4; ++ni)
          acc[mi][ni] = __builtin_amdgcn_mfma_f32_16x16x32_bf16(af[mi], bf[ni], acc[mi][ni], 0, 0, 0);
    }
    __syncthreads();
  }

#pragma unroll
  for (int mi = 0; mi < 4; ++mi) {
#pragma unroll
    for (int ni = 0; ni < 4; ++ni) {
      const int n = browbase + wn * 64 + ni * 16 + lq;
      const unsigned s = (unsigned)n / 768u;
      const int rem = n - (int)s * 768;
      const int hh = rem >> 6, d = rem & 63;
#pragma unroll
      for (int j = 0; j < 4; ++j) {
        const int m = arowbase + wm * 64 + mi * 16 + grp * 4 + j;
        if (m < MROWS) {
          const unsigned bb = (unsigned)m / 577u;
          const int t = m - (int)bb * 577;
          const unsigned short bv = f2bf(acc[mi][ni][j]);
          const size_t bh = (size_t)bb * H_ + hh;
          if (s == 0)      qb  [(bh * NPAD + t) * HD_ + d] = bv;
          else if (s == 1) kbuf[(bh * NPAD + t) * HD_ + d] = bv;
          else             vtb [(bh * HD_ + d) * NPAD + t] = bv;
        }
      }
    }
  }
}

// ---------------- Fused attention: scores (pre-softmax, f32) + O = softmax(S) @ V ----------------
// No-max softmax (scores bounded ~|10|). K, V, prev all prefetched one full
// iteration ahead; loop fully unrolled so 9/10 iterations have compile-time
// bounds and rotates become renames. 1D grid swizzled so all 10 q-blocks of
// one (b,h) share an XCD -> K/V are same-L2-resident.
__global__ __launch_bounds__(256, 3) void attn_kernel(
    const unsigned short* __restrict__ qb,
    const unsigned short* __restrict__ kb,
    const unsigned short* __restrict__ vtb,
    const float* __restrict__ prev,
    float* __restrict__ scores_out,   // d_out + OUT0_ELTS
    unsigned short* __restrict__ ob)  // [MPAD][768] bf16
{
  const int wgid = blockIdx.x;            // 0..3839
  const int xcd  = wgid & 7;              // dispatch round-robins wgid%8 -> XCD
  const int j    = wgid >> 3;             // 0..479 within this XCD
  const int jd   = j / 10;
  const int bh   = xcd * 48 + jd;         // 48 bh per XCD
  const int qblk = j - jd * 10;           // 0..9

  const int wave = threadIdx.x >> 6;
  const int lane = threadIdx.x & 63;
  const int lq = lane & 15, grp = lane >> 4;

  const int b = bh / H_;
  const int h = bh - b * H_;

  const unsigned short* qp = qb  + (size_t)bh * NPAD * HD_;
  const unsigned short* kp = kb  + (size_t)bh * NPAD * HD_;
  const unsigned short* vp = vtb + (size_t)bh * HD_ * NPAD;

  const int qrow = qblk * 64 + wave * 16 + lq;
  const bool qvalid = (qrow < N_);

  const float* prevrow = prev + ((size_t)bh * N_ + qrow) * N_;
  float* srow = scores_out + ((size_t)bh * N_ + qrow) * N_;

  short8 qf0, qf1;
  {
    const unsigned short* qr = qp + (size_t)qrow * HD_ + grp * 8;
    qf0 = *(const short8*)(qr);
    qf1 = *(const short8*)(qr + 32);
  }

  f32x4 oacc[4] = {};
  float lacc = 0.f;   // per-lane partial sum of exp; cross-lane reduce after loop

  __shared__ __attribute__((aligned(16))) unsigned short plds[2][4][16][72];

  // ---- load helpers ----
  auto loadK = [&](int kblk, short8 kf[8]) {
#pragma unroll
    for (int t = 0; t < 4; ++t) {
      const unsigned short* kr = kp + (size_t)(kblk * 64 + t * 16 + lq) * HD_ + grp * 8;
      kf[2 * t]     = *(const short8*)(kr);
      kf[2 * t + 1] = *(const short8*)(kr + 32);
    }
  };
  auto loadV = [&](int kblk, short8 vf[8]) {
#pragma unroll
    for (int dt = 0; dt < 4; ++dt) {
      const unsigned short* vr = vp + (size_t)(dt * 16 + lq) * NPAD + kblk * 64 + grp * 8;
      vf[2 * dt]     = *(const short8*)(vr);
      vf[2 * dt + 1] = *(const short8*)(vr + 32);
    }
  };
  auto loadPrev = [&](int kblk, float pv[16]) {
#pragma unroll
    for (int t = 0; t < 4; ++t) {
      const int kg0 = kblk * 64 + t * 16 + grp * 4;
      float tmp[4] = {0.f, 0.f, 0.f, 0.f};
      if (qvalid) {
        if (kg0 + 3 < N_) {
          __builtin_memcpy(tmp, prevrow + kg0, 16);   // rows only 4B-aligned
        } else {
#pragma unroll
          for (int e = 0; e < 4; ++e)
            if (kg0 + e < N_) tmp[e] = prevrow[kg0 + e];
        }
      }
#pragma unroll
      for (int e = 0; e < 4; ++e) pv[t * 4 + e] = tmp[e];
    }
  };

  short8 kf[8], vf[8];
  float  pv[16];
  loadK(0, kf);
  loadV(0, vf);
  loadPrev(0, pv);

#pragma unroll
  for (int kblk = 0; kblk < 10; ++kblk) {
    const int kbase = kblk * 64;

    // 1. prefetch next prev tile (the only HBM-cold stream)
    float pvn[16];
    if (kblk < 9) loadPrev(kblk + 1, pvn);

    // 2. S^T = K @ Q^T  (per lane: col = q = lq, row = k-in-tile = grp*4+reg)
    f32x4 sacc[4] = {};
#pragma unroll
    for (int t = 0; t < 4; ++t) {
      sacc[t] = __builtin_amdgcn_mfma_f32_16x16x32_bf16(kf[2 * t],     qf0, sacc[t], 0, 0, 0);
      sacc[t] = __builtin_amdgcn_mfma_f32_16x16x32_bf16(kf[2 * t + 1], qf1, sacc[t], 0, 0, 0);
    }

    // 3. prefetch next K and V — consumed next iteration
    short8 kfn[8], vfn[8];
    if (kblk < 9) { loadK(kblk + 1, kfn); loadV(kblk + 1, vfn); }

    // 4. scale + prev, write scores, exponentiate (no max subtraction)
    float p[16];
#pragma unroll
    for (int t = 0; t < 4; ++t) {
      const int kg0 = kbase + t * 16 + grp * 4;
      float sv[4];
#pragma unroll
      for (int r = 0; r < 4; ++r) {
        float sval = sacc[t][r] * SCALE + pv[t * 4 + r];
        if (kg0 + r >= N_) sval = -__builtin_inff();
        sv[r] = sval;
        float e = __expf(sval);
        p[t * 4 + r] = e;
        lacc += e;
      }
      if (qvalid) {
        if (kg0 + 3 < N_) {
          __builtin_memcpy(srow + kg0, sv, 16);
        } else {
#pragma unroll
          for (int e2 = 0; e2 < 4; ++e2)
            if (kg0 + e2 < N_) srow[kg0 + e2] = sv[e2];
        }
      }
    }

    // 5. P -> LDS (double-buffered; row q = lq, contiguous k), read back as B-fragments
    const int pb = kblk & 1;
#pragma unroll
    for (int t = 0; t < 4; ++t) {
      ushort4v pw;
      pw.x = f2bf(p[t * 4 + 0]); pw.y = f2bf(p[t * 4 + 1]);
      pw.z = f2bf(p[t * 4 + 2]); pw.w = f2bf(p[t * 4 + 3]);
      *(ushort4v*)(&plds[pb][wave][lq][t * 16 + grp * 4]) = pw;
    }
    short8 pf0 = *(const short8*)(&plds[pb][wave][lq][grp * 8]);
    short8 pf1 = *(const short8*)(&plds[pb][wave][lq][32 + grp * 8]);

    // 6. O^T += V^T @ P^T  (vf loaded one iteration ago — latency covered)
#pragma unroll
    for (int dt = 0; dt < 4; ++dt) {
      oacc[dt] = __builtin_amdgcn_mfma_f32_16x16x32_bf16(vf[2 * dt],     pf0, oacc[dt], 0, 0, 0);
      oacc[dt] = __builtin_amdgcn_mfma_f32_16x16x32_bf16(vf[2 * dt + 1], pf1, oacc[dt], 0, 0, 0);
    }

    // 7. rotate (renamed away by full unroll)
    if (kblk < 9) {
#pragma unroll
      for (int i = 0; i < 16; ++i) pv[i] = pvn[i];
#pragma unroll
      for (int i = 0; i < 8; ++i) { kf[i] = kfn[i]; vf[i] = vfn[i]; }
    }
  }

  // deferred l-reduce: lanes ^16, ^32 hold the other k-subsets of the same q-row
  lacc += __shfl_xor(lacc, 16, 64);
  lacc += __shfl_xor(lacc, 32, 64);

  if (qvalid) {
    const float rl = 1.0f / lacc;
    unsigned short* orow = ob + (size_t)(b * N_ + qrow) * C_ + h * HD_;
#pragma unroll
    for (int dt = 0; dt < 4; ++dt) {
      ushort4v ow;
      ow.x = f2bf(oacc[dt][0] * rl); ow.y = f2bf(oacc[dt][1] * rl);
      ow.z = f2bf(oacc[dt][2] * rl); ow.w = f2bf(oacc[dt][3] * rl);
      *(ushort4v*)(orow + dt * 16 + grp * 4) = ow;
    }
  }
}

// ---------------- Proj GEMM: out0[m,n] = sum_k ob[m,k]*Wproj[n,k] + bias[n] ----------------
__global__ __launch_bounds__(256) void gemm_proj(
    const unsigned short* __restrict__ A,    // ob [MPAD][768]
    const unsigned short* __restrict__ Bw,   // wprojb [768][768]
    const float* __restrict__ bias,
    float* __restrict__ out0)
{
  __shared__ unsigned short As[128 * 64];
  __shared__ unsigned short Bs[128 * 64];
  const int mt = blockIdx.x, nt = blockIdx.y;
  const int tid = threadIdx.x;
  const int wave = tid >> 6, lane = tid & 63;
  const int wm = wave >> 1, wn = wave & 1;
  const int lq = lane & 15, grp = lane >> 4;

  f32x4 acc[4][4] = {};

  const int arowbase = mt * 128;
  const int browbase = nt * 128;
  const int srow = wave * 8 + (lane >> 3);
  const int scol = (lane & 7) * 8;

  for (int kblk = 0; kblk < 12; ++kblk) {
    const int koff = kblk * 64;
#pragma unroll
    for (int i = 0; i < 4; ++i) {
      gload_lds16(A  + (size_t)(arowbase + i * 32 + srow) * 768 + koff + scol,
                  &As[(i * 32 + wave * 8) * 64]);
      gload_lds16(Bw + (size_t)(browbase + i * 32 + srow) * 768 + koff + scol,
                  &Bs[(i * 32 + wave * 8) * 64]);
    }
    __syncthreads();
#pragma unroll
    for (int ks = 0; ks < 2; ++ks) {
      short8 af[4], bf[4];
#pragma unroll
      for (int mi = 0; mi < 4; ++mi)
        af[mi] = *(const short8*)&As[(wm * 64 + mi * 16 + lq) * 64 + ks * 32 + grp * 8];
#pragma unroll
      for (int ni = 0; ni < 4; ++ni)
        bf[ni] = *(const short8*)&Bs[(wn * 64 + ni * 16 + lq) * 64 + ks * 32 + grp * 8];
#pragma unroll
      for (int mi = 0; mi < 4; ++mi)
#pragma unroll
        for (int ni = 0; ni < 4; ++ni)
          acc[mi][ni] = __builtin_amdgcn_mfma_f32_16x16x32_bf16(af[mi], bf[ni], acc[mi][ni], 0, 0, 0);
    }
    __syncthreads();
  }

#pragma unroll
  for (int ni = 0; ni < 4; ++ni) {
    const int n = browbase + wn * 64 + ni * 16 + lq;
    const float bv = bias[n];
#pragma unroll
    for (int mi = 0; mi < 4; ++mi) {
#pragma unroll
      for (int j = 0; j < 4; ++j) {
        const int m = arowbase + wm * 64 + mi * 16 + grp * 4 + j;
        if (m < MROWS) out0[(size_t)m * C_ + n] = acc[mi][ni][j] + bv;
      }
    }
  }
}

// ---------------- launch ----------------
extern "C" void kernel_launch(void* const* d_in, const int* in_sizes, int n_in,
                              void* d_out, int out_size, void* d_ws, size_t ws_size,
                              hipStream_t stream) {
  const float* x     = (const float*)d_in[0];
  const float* prev  = (const float*)d_in[1];
  const float* Wqkv  = (const float*)d_in[2];
  const float* Wproj = (const float*)d_in[3];
  const float* bproj = (const float*)d_in[4];
  float* out = (float*)d_out;

  char* ws = (char*)d_ws;
  size_t off = 0;
  auto alloc = [&](size_t bytes) {
    void* p = ws + off;
    off += (bytes + 255) & ~(size_t)255;
    return p;
  };
  unsigned short* xb     = (unsigned short*)alloc((size_t)MPAD * 768 * 2);
  unsigned short* wqkvb  = (unsigned short*)alloc((size_t)NQKV * 768 * 2);
  unsigned short* wprojb = (unsigned short*)alloc((size_t)768 * 768 * 2);
  unsigned short* qb     = (unsigned short*)alloc((size_t)B_ * H_ * NPAD * HD_ * 2);
  unsigned short* kbuf   = (unsigned short*)alloc((size_t)B_ * H_ * NPAD * HD_ * 2);
  unsigned short* vtb    = (unsigned short*)alloc((size_t)B_ * H_ * HD_ * NPAD * 2);
  unsigned short* ob     = (unsigned short*)alloc((size_t)MPAD * 768 * 2);
  (void)ob;

  // Only vtb's padding must be guaranteed finite: PV multiplies P=0 by pad V
  // columns, and 0 * NaN = NaN in MFMA. All other pad values are discarded
  // arithmetically (masked to -inf or dropped by m<MROWS / qvalid guards).
  hipMemsetAsync(vtb, 0, (size_t)B_ * H_ * HD_ * NPAD * 2, stream);

  {
    int n4 = (B_ * N_ * C_) / 4;
    cvt_f32_bf16<<<(n4 + 255) / 256, 256, 0, stream>>>(x, xb, n4);
    n4 = (NQKV * C_) / 4;
    cvt_f32_bf16<<<(n4 + 255) / 256, 256, 0, stream>>>(Wqkv, wqkvb, n4);
    n4 = (C_ * C_) / 4;
    cvt_f32_bf16<<<(n4 + 255) / 256, 256, 0, stream>>>(Wproj, wprojb, n4);
  }

  gemm_qkv<<<dim3(MPAD / 128, NQKV / 128), 256, 0, stream>>>(xb, wqkvb, qb, kbuf, vtb);

  attn_kernel<<<dim3(3840), 256, 0, stream>>>(qb, kbuf, vtb, prev,
                                              out + OUT0_ELTS, ob);

  gemm_proj<<<dim3(MPAD / 128, C_ / 128), 256, 0, stream>>>(ob, wprojb, bproj, out);
}

// Round 6
// 611.494 us; speedup vs baseline: 1.9576x; 1.9576x over previous
//
#include <hip/hip_runtime.h>
#include <cstdint>
#include <cstddef>

using short8   = __attribute__((ext_vector_type(8))) short;
using f32x4    = __attribute__((ext_vector_type(4))) float;
using ushort4v = __attribute__((ext_vector_type(4))) unsigned short;

#define B_    32
#define N_    577
#define C_    768
#define H_    12
#define HD_   64
#define NPAD  640
#define MROWS 18464   // B*N
#define MPAD  18560   // 145*128
#define NQKV  2304    // 3*C
#define SCALE 0.125f
#define OUT0_ELTS 14180352   // B*N*C

static __device__ __forceinline__ unsigned short f2bf(float f) {
  union { float f; unsigned int u; } v; v.f = f;
  return (unsigned short)((v.u + 0x7FFFu + ((v.u >> 16) & 1u)) >> 16);
}

static __device__ __forceinline__ void gload_lds16(const unsigned short* g, unsigned short* l) {
  __builtin_amdgcn_global_load_lds(
      (const __attribute__((address_space(1))) unsigned int*)g,
      (__attribute__((address_space(3))) unsigned int*)l, 16, 0, 0);
}

// ---------------- f32 -> bf16 convert ----------------
__global__ __launch_bounds__(256) void cvt_f32_bf16(const float* __restrict__ src,
                                                    unsigned short* __restrict__ dst, int n4) {
  int i = blockIdx.x * 256 + threadIdx.x;
  if (i >= n4) return;
  f32x4 v = ((const f32x4*)src)[i];
  ushort4v o;
  o.x = f2bf(v.x); o.y = f2bf(v.y); o.z = f2bf(v.z); o.w = f2bf(v.w);
  ((ushort4v*)dst)[i] = o;
}

// ---------------- QKV GEMM: C[m,n] = sum_k xb[m,k]*Wqkv[n,k], scatter to q/k/vT ----------------
__global__ __launch_bounds__(256) void gemm_qkv(
    const unsigned short* __restrict__ A,    // xb [MPAD][768]
    const unsigned short* __restrict__ Bw,   // wqkvb [2304][768]
    unsigned short* __restrict__ qb,         // [B*H][640][64]
    unsigned short* __restrict__ kbuf,       // [B*H][640][64]
    unsigned short* __restrict__ vtb)        // [B*H][64][640]
{
  __shared__ unsigned short As[128 * 64];
  __shared__ unsigned short Bs[128 * 64];
  const int mt = blockIdx.x, nt = blockIdx.y;
  const int tid = threadIdx.x;
  const int wave = tid >> 6, lane = tid & 63;
  const int wm = wave >> 1, wn = wave & 1;
  const int lq = lane & 15, grp = lane >> 4;

  f32x4 acc[4][4] = {};

  const int arowbase = mt * 128;
  const int browbase = nt * 128;
  const int srow = wave * 8 + (lane >> 3);
  const int scol = (lane & 7) * 8;

  for (int kblk = 0; kblk < 12; ++kblk) {
    const int koff = kblk * 64;
#pragma unroll
    for (int i = 0; i < 4; ++i) {
      gload_lds16(A  + (size_t)(arowbase + i * 32 + srow) * 768 + koff + scol,
                  &As[(i * 32 + wave * 8) * 64]);
      gload_lds16(Bw + (size_t)(browbase + i * 32 + srow) * 768 + koff + scol,
                  &Bs[(i * 32 + wave * 8) * 64]);
    }
    __syncthreads();
#pragma unroll
    for (int ks = 0; ks < 2; ++ks) {
      short8 af[4], bf[4];
#pragma unroll
      for (int mi = 0; mi < 4; ++mi)
        af[mi] = *(const short8*)&As[(wm * 64 + mi * 16 + lq) * 64 + ks * 32 + grp * 8];
#pragma unroll
      for (int ni = 0; ni < 4; ++ni)
        bf[ni] = *(const short8*)&Bs[(wn * 64 + ni * 16 + lq) * 64 + ks * 32 + grp * 8];
#pragma unroll
      for (int mi = 0; mi < 4; ++mi)
#pragma unroll
        for (int ni = 0; ni < 4; ++ni)
          acc[mi][ni] = __builtin_amdgcn_mfma_f32_16x16x32_bf16(af[mi], bf[ni], acc[mi][ni], 0, 0, 0);
    }
    __syncthreads();
  }

#pragma unroll
  for (int mi = 0; mi < 4; ++mi) {
#pragma unroll
    for (int ni = 0; ni < 4; ++ni) {
      const int n = browbase + wn * 64 + ni * 16 + lq;
      const unsigned s = (unsigned)n / 768u;
      const int rem = n - (int)s * 768;
      const int hh = rem >> 6, d = rem & 63;
#pragma unroll
      for (int j = 0; j < 4; ++j) {
        const int m = arowbase + wm * 64 + mi * 16 + grp * 4 + j;
        if (m < MROWS) {
          const unsigned bb = (unsigned)m / 577u;
          const int t = m - (int)bb * 577;
          const unsigned short bv = f2bf(acc[mi][ni][j]);
          const size_t bh = (size_t)bb * H_ + hh;
          if (s == 0)      qb  [(bh * NPAD + t) * HD_ + d] = bv;
          else if (s == 1) kbuf[(bh * NPAD + t) * HD_ + d] = bv;
          else             vtb [(bh * HD_ + d) * NPAD + t] = bv;
        }
      }
    }
  }
}

// ---------------- Fused attention ----------------
// v6: machine-side coalescing. K/V tiles staged ONCE per block into LDS via
// global_load_lds (contiguous 1KB wave-segments, source-XOR-swizzled so the
// b128 fragment reads are bank-uniform), double-buffered with one
// __syncthreads per iteration (full-iteration prefetch cover via its vmcnt0
// drain). Scores go through a wave-PRIVATE padded LDS slab: computed in
// MFMA S^T layout, stored coalesced (4 rows x 256B per wave-instr), and P
// fragments are re-read from the slab in [q][k] layout (plds removed).
// No-max softmax (scores bounded); prev stays register-prefetched 1-ahead.
__global__ __launch_bounds__(256, 3) void attn_kernel(
    const unsigned short* __restrict__ qb,
    const unsigned short* __restrict__ kb,
    const unsigned short* __restrict__ vtb,
    const float* __restrict__ prev,
    float* __restrict__ scores_out,   // d_out + OUT0_ELTS
    unsigned short* __restrict__ ob)  // [MPAD][768] bf16
{
  const int qblk = blockIdx.x;   // 0..9
  const int bh   = blockIdx.y;   // 0..383
  const int tid  = threadIdx.x;
  const int wave = tid >> 6;
  const int lane = tid & 63;
  const int lq = lane & 15, grp = lane >> 4;

  const int b = bh / H_;
  const int h = bh - b * H_;

  const unsigned short* qp = qb  + (size_t)bh * NPAD * HD_;
  const unsigned short* kp = kb  + (size_t)bh * NPAD * HD_;
  const unsigned short* vp = vtb + (size_t)bh * HD_ * NPAD;

  const int qrow = qblk * 64 + wave * 16 + lq;
  const bool qvalid = (qrow < N_);

  const float* prevrow = prev + ((size_t)bh * N_ + qrow) * N_;
  float* srow_base = scores_out + (size_t)bh * N_ * N_;

  // K/V tile buffers: [buf][64 rows][64 bf16], chunk c of row r stored at
  // slot (c ^ (r&7)) -> conflict-free b128 reads. 8 KB each, double-buffered.
  __shared__ __attribute__((aligned(16))) unsigned short ldsK[2][4096];
  __shared__ __attribute__((aligned(16))) unsigned short ldsV[2][4096];
  // Per-wave private scores slab [16 q][64 k], +4 pad -> conflict-free.
  __shared__ __attribute__((aligned(16))) float sslab[4][16][68];

  short8 qf0, qf1;
  {
    const unsigned short* qr = qp + (size_t)qrow * HD_ + grp * 8;
    qf0 = *(const short8*)(qr);
    qf1 = *(const short8*)(qr + 32);
  }

  f32x4 oacc[4] = {};
  float lacc = 0.f;

  // staging: thread covers slot (r*256+tid); row = r*32 + (tid>>3),
  // chunk c = (tid&7) ^ ((tid>>3)&7); dest is wave-uniform + lane*16.
  const int rhi = tid >> 3;                       // 0..31
  const int chk = (tid & 7) ^ (rhi & 7);
  auto stageKV = [&](int kblk, int bufi) {
    const int kbase = kblk * 64;
#pragma unroll
    for (int r = 0; r < 2; ++r) {
      gload_lds16(kp + (size_t)(kbase + r * 32 + rhi) * HD_ + chk * 8,
                  &ldsK[bufi][r * 2048 + wave * 512]);
      gload_lds16(vp + (size_t)(r * 32 + rhi) * NPAD + kbase + chk * 8,
                  &ldsV[bufi][r * 2048 + wave * 512]);
    }
  };

  auto loadPrev = [&](int kblk, float pv[16]) {
#pragma unroll
    for (int t = 0; t < 4; ++t) {
      const int kg0 = kblk * 64 + t * 16 + grp * 4;
      float tmp[4] = {0.f, 0.f, 0.f, 0.f};
      if (qvalid) {
        if (kg0 + 3 < N_) {
          __builtin_memcpy(tmp, prevrow + kg0, 16);   // rows only 4B-aligned
        } else {
#pragma unroll
          for (int e = 0; e < 4; ++e)
            if (kg0 + e < N_) tmp[e] = prevrow[kg0 + e];
        }
      }
#pragma unroll
      for (int e = 0; e < 4; ++e) pv[t * 4 + e] = tmp[e];
    }
  };

  // swizzled fragment slots (ushort offsets within a row's 64 ushorts)
  const int sl0 = ((grp)     ^ (lq & 7)) * 8;   // chunk grp   (k/d 0..31 half)
  const int sl1 = ((grp + 4) ^ (lq & 7)) * 8;   // chunk grp+4 (k/d 32..63 half)

  float pv[16], pvn[16];
  stageKV(0, 0);
  loadPrev(0, pv);

#pragma unroll 1
  for (int kblk = 0; kblk < 10; ++kblk) {
    // Drains vmcnt(0): KV[cur] staged last iteration is now in LDS for all
    // waves; prev prefetch arrived; old scores stores retired.
    __syncthreads();
    const int cur = kblk & 1;
    const int kbase = kblk * 64;

    // prefetch next tile + next prev — a full iteration of latency cover
    if (kblk < 9) {
      stageKV(kblk + 1, cur ^ 1);
      loadPrev(kblk + 1, pvn);
    }

    // S^T = K @ Q^T from LDS (per lane: col=q=lq, row=k-in-tile=grp*4+reg)
    f32x4 sacc[4] = {};
#pragma unroll
    for (int t = 0; t < 4; ++t) {
      const int row = (t * 16 + lq) * 64;
      short8 a0 = *(const short8*)&ldsK[cur][row + sl0];
      short8 a1 = *(const short8*)&ldsK[cur][row + sl1];
      sacc[t] = __builtin_amdgcn_mfma_f32_16x16x32_bf16(a0, qf0, sacc[t], 0, 0, 0);
      sacc[t] = __builtin_amdgcn_mfma_f32_16x16x32_bf16(a1, qf1, sacc[t], 0, 0, 0);
    }

    // scale + prev, mask, write into this wave's slab in [q][k] layout
#pragma unroll
    for (int t = 0; t < 4; ++t) {
      const int kg0 = kbase + t * 16 + grp * 4;
      f32x4 sv;
#pragma unroll
      for (int r = 0; r < 4; ++r) {
        float sval = sacc[t][r] * SCALE + pv[t * 4 + r];
        if (kg0 + r >= N_) sval = -__builtin_inff();
        sv[r] = sval;
      }
      *(f32x4*)&sslab[wave][lq][t * 16 + grp * 4] = sv;
    }

    // P fragments: read own q-row back in [q][k] layout, exp, pack bf16
    short8 pf0, pf1;
    {
      const float* sr = &sslab[wave][lq][0];
      f32x4 x0 = *(const f32x4*)(sr + grp * 8);
      f32x4 x1 = *(const f32x4*)(sr + grp * 8 + 4);
      f32x4 x2 = *(const f32x4*)(sr + 32 + grp * 8);
      f32x4 x3 = *(const f32x4*)(sr + 32 + grp * 8 + 4);
      float e[16];
#pragma unroll
      for (int j = 0; j < 4; ++j) {
        e[j]      = __expf(x0[j]);
        e[4 + j]  = __expf(x1[j]);
        e[8 + j]  = __expf(x2[j]);
        e[12 + j] = __expf(x3[j]);
      }
#pragma unroll
      for (int j = 0; j < 16; ++j) lacc += e[j];
      ushort4v pa, pb2, pc, pd;
#pragma unroll
      for (int j = 0; j < 4; ++j) {
        ((unsigned short*)&pa)[j]  = f2bf(e[j]);
        ((unsigned short*)&pb2)[j] = f2bf(e[4 + j]);
        ((unsigned short*)&pc)[j]  = f2bf(e[8 + j]);
        ((unsigned short*)&pd)[j]  = f2bf(e[12 + j]);
      }
      union { struct { ushort4v a, b; } s; short8 v; } u0, u1;
      u0.s.a = pa; u0.s.b = pb2; pf0 = u0.v;
      u1.s.a = pc; u1.s.b = pd;  pf1 = u1.v;
    }

    // O^T += V^T @ P^T from LDS
#pragma unroll
    for (int dt = 0; dt < 4; ++dt) {
      const int row = (dt * 16 + lq) * 64;
      short8 v0 = *(const short8*)&ldsV[cur][row + sl0];
      short8 v1 = *(const short8*)&ldsV[cur][row + sl1];
      oacc[dt] = __builtin_amdgcn_mfma_f32_16x16x32_bf16(v0, pf0, oacc[dt], 0, 0, 0);
      oacc[dt] = __builtin_amdgcn_mfma_f32_16x16x32_bf16(v1, pf1, oacc[dt], 0, 0, 0);
    }

    // cooperative coalesced scores store of own slab rows:
    // per round, this wave stores 4 rows x 256 B contiguous.
#pragma unroll
    for (int q4 = 0; q4 < 4; ++q4) {
      const int row16 = q4 * 4 + (lane >> 4);
      const int qrow_s = qblk * 64 + wave * 16 + row16;
      const int col0 = (lane & 15) * 4;
      const int kg = kbase + col0;
      if (qrow_s < N_) {
        f32x4 vals = *(const f32x4*)&sslab[wave][row16][col0];
        float* dst = srow_base + (size_t)qrow_s * N_ + kg;
        if (kg + 3 < N_) {
          __builtin_memcpy(dst, &vals, 16);
        } else {
#pragma unroll
          for (int e2 = 0; e2 < 4; ++e2)
            if (kg + e2 < N_) dst[e2] = vals[e2];
        }
      }
    }

    if (kblk < 9) {
#pragma unroll
      for (int i = 0; i < 16; ++i) pv[i] = pvn[i];
    }
  }

  // deferred l-reduce: lanes ^16, ^32 hold the other k-subsets of the same q-row
  lacc += __shfl_xor(lacc, 16, 64);
  lacc += __shfl_xor(lacc, 32, 64);

  if (qvalid) {
    const float rl = 1.0f / lacc;
    unsigned short* orow = ob + (size_t)(b * N_ + qrow) * C_ + h * HD_;
#pragma unroll
    for (int dt = 0; dt < 4; ++dt) {
      ushort4v ow;
      ow.x = f2bf(oacc[dt][0] * rl); ow.y = f2bf(oacc[dt][1] * rl);
      ow.z = f2bf(oacc[dt][2] * rl); ow.w = f2bf(oacc[dt][3] * rl);
      *(ushort4v*)(orow + dt * 16 + grp * 4) = ow;
    }
  }
}

// ---------------- Proj GEMM: out0[m,n] = sum_k ob[m,k]*Wproj[n,k] + bias[n] ----------------
__global__ __launch_bounds__(256) void gemm_proj(
    const unsigned short* __restrict__ A,    // ob [MPAD][768]
    const unsigned short* __restrict__ Bw,   // wprojb [768][768]
    const float* __restrict__ bias,
    float* __restrict__ out0)
{
  __shared__ unsigned short As[128 * 64];
  __shared__ unsigned short Bs[128 * 64];
  const int mt = blockIdx.x, nt = blockIdx.y;
  const int tid = threadIdx.x;
  const int wave = tid >> 6, lane = tid & 63;
  const int wm = wave >> 1, wn = wave & 1;
  const int lq = lane & 15, grp = lane >> 4;

  f32x4 acc[4][4] = {};

  const int arowbase = mt * 128;
  const int browbase = nt * 128;
  const int srow = wave * 8 + (lane >> 3);
  const int scol = (lane & 7) * 8;

  for (int kblk = 0; kblk < 12; ++kblk) {
    const int koff = kblk * 64;
#pragma unroll
    for (int i = 0; i < 4; ++i) {
      gload_lds16(A  + (size_t)(arowbase + i * 32 + srow) * 768 + koff + scol,
                  &As[(i * 32 + wave * 8) * 64]);
      gload_lds16(Bw + (size_t)(browbase + i * 32 + srow) * 768 + koff + scol,
                  &Bs[(i * 32 + wave * 8) * 64]);
    }
    __syncthreads();
#pragma unroll
    for (int ks = 0; ks < 2; ++ks) {
      short8 af[4], bf[4];
#pragma unroll
      for (int mi = 0; mi < 4; ++mi)
        af[mi] = *(const short8*)&As[(wm * 64 + mi * 16 + lq) * 64 + ks * 32 + grp * 8];
#pragma unroll
      for (int ni = 0; ni < 4; ++ni)
        bf[ni] = *(const short8*)&Bs[(wn * 64 + ni * 16 + lq) * 64 + ks * 32 + grp * 8];
#pragma unroll
      for (int mi = 0; mi < 4; ++mi)
#pragma unroll
        for (int ni = 0; ni < 4; ++ni)
          acc[mi][ni] = __builtin_amdgcn_mfma_f32_16x16x32_bf16(af[mi], bf[ni], acc[mi][ni], 0, 0, 0);
    }
    __syncthreads();
  }

#pragma unroll
  for (int ni = 0; ni < 4; ++ni) {
    const int n = browbase + wn * 64 + ni * 16 + lq;
    const float bv = bias[n];
#pragma unroll
    for (int mi = 0; mi < 4; ++mi) {
#pragma unroll
      for (int j = 0; j < 4; ++j) {
        const int m = arowbase + wm * 64 + mi * 16 + grp * 4 + j;
        if (m < MROWS) out0[(size_t)m * C_ + n] = acc[mi][ni][j] + bv;
      }
    }
  }
}

// ---------------- launch ----------------
extern "C" void kernel_launch(void* const* d_in, const int* in_sizes, int n_in,
                              void* d_out, int out_size, void* d_ws, size_t ws_size,
                              hipStream_t stream) {
  const float* x     = (const float*)d_in[0];
  const float* prev  = (const float*)d_in[1];
  const float* Wqkv  = (const float*)d_in[2];
  const float* Wproj = (const float*)d_in[3];
  const float* bproj = (const float*)d_in[4];
  float* out = (float*)d_out;

  char* ws = (char*)d_ws;
  size_t off = 0;
  auto alloc = [&](size_t bytes) {
    void* p = ws + off;
    off += (bytes + 255) & ~(size_t)255;
    return p;
  };
  unsigned short* xb     = (unsigned short*)alloc((size_t)MPAD * 768 * 2);
  unsigned short* wqkvb  = (unsigned short*)alloc((size_t)NQKV * 768 * 2);
  unsigned short* wprojb = (unsigned short*)alloc((size_t)768 * 768 * 2);
  unsigned short* qb     = (unsigned short*)alloc((size_t)B_ * H_ * NPAD * HD_ * 2);
  unsigned short* kbuf   = (unsigned short*)alloc((size_t)B_ * H_ * NPAD * HD_ * 2);
  unsigned short* vtb    = (unsigned short*)alloc((size_t)B_ * H_ * HD_ * NPAD * 2);
  unsigned short* ob     = (unsigned short*)alloc((size_t)MPAD * 768 * 2);
  (void)ob;

  // Only vtb's padding must be guaranteed finite: PV multiplies P=0 by pad V
  // columns, and 0 * NaN = NaN in MFMA. All other pad values are discarded
  // arithmetically (masked to -inf or dropped by m<MROWS / qvalid guards).
  hipMemsetAsync(vtb, 0, (size_t)B_ * H_ * HD_ * NPAD * 2, stream);

  {
    int n4 = (B_ * N_ * C_) / 4;
    cvt_f32_bf16<<<(n4 + 255) / 256, 256, 0, stream>>>(x, xb, n4);
    n4 = (NQKV * C_) / 4;
    cvt_f32_bf16<<<(n4 + 255) / 256, 256, 0, stream>>>(Wqkv, wqkvb, n4);
    n4 = (C_ * C_) / 4;
    cvt_f32_bf16<<<(n4 + 255) / 256, 256, 0, stream>>>(Wproj, wprojb, n4);
  }

  gemm_qkv<<<dim3(MPAD / 128, NQKV / 128), 256, 0, stream>>>(xb, wqkvb, qb, kbuf, vtb);

  attn_kernel<<<dim3(10, B_ * H_), 256, 0, stream>>>(qb, kbuf, vtb, prev,
                                                     out + OUT0_ELTS, ob);

  gemm_proj<<<dim3(MPAD / 128, C_ / 128), 256, 0, stream>>>(ob, wprojb, bproj, out);
}

// Round 7
// 605.149 us; speedup vs baseline: 1.9781x; 1.0105x over previous
//
#include <hip/hip_runtime.h>
#include <cstdint>
#include <cstddef>

using short8   = __attribute__((ext_vector_type(8))) short;
using f32x4    = __attribute__((ext_vector_type(4))) float;
using ushort4v = __attribute__((ext_vector_type(4))) unsigned short;

#define B_    32
#define N_    577
#define C_    768
#define H_    12
#define HD_   64
#define NPAD  640
#define MROWS 18464   // B*N
#define MPAD  18560   // 145*128
#define NQKV  2304    // 3*C
#define SCALE 0.125f
#define OUT0_ELTS 14180352   // B*N*C

static __device__ __forceinline__ unsigned short f2bf(float f) {
  union { float f; unsigned int u; } v; v.f = f;
  return (unsigned short)((v.u + 0x7FFFu + ((v.u >> 16) & 1u)) >> 16);
}

static __device__ __forceinline__ void gload_lds16(const unsigned short* g, unsigned short* l) {
  __builtin_amdgcn_global_load_lds(
      (const __attribute__((address_space(1))) unsigned int*)g,
      (__attribute__((address_space(3))) unsigned int*)l, 16, 0, 0);
}

// ---------------- f32 -> bf16 convert ----------------
__global__ __launch_bounds__(256) void cvt_f32_bf16(const float* __restrict__ src,
                                                    unsigned short* __restrict__ dst, int n4) {
  int i = blockIdx.x * 256 + threadIdx.x;
  if (i >= n4) return;
  f32x4 v = ((const f32x4*)src)[i];
  ushort4v o;
  o.x = f2bf(v.x); o.y = f2bf(v.y); o.z = f2bf(v.z); o.w = f2bf(v.w);
  ((ushort4v*)dst)[i] = o;
}

// ---------------- QKV GEMM: C[m,n] = sum_k xb[m,k]*Wqkv[n,k], scatter to q/k/vT ----------------
__global__ __launch_bounds__(256) void gemm_qkv(
    const unsigned short* __restrict__ A,    // xb [MPAD][768]
    const unsigned short* __restrict__ Bw,   // wqkvb [2304][768]
    unsigned short* __restrict__ qb,         // [B*H][640][64]
    unsigned short* __restrict__ kbuf,       // [B*H][640][64]
    unsigned short* __restrict__ vtb)        // [B*H][64][640]
{
  __shared__ unsigned short As[128 * 64];
  __shared__ unsigned short Bs[128 * 64];
  const int mt = blockIdx.x, nt = blockIdx.y;
  const int tid = threadIdx.x;
  const int wave = tid >> 6, lane = tid & 63;
  const int wm = wave >> 1, wn = wave & 1;
  const int lq = lane & 15, grp = lane >> 4;

  f32x4 acc[4][4] = {};

  const int arowbase = mt * 128;
  const int browbase = nt * 128;
  const int srow = wave * 8 + (lane >> 3);
  const int scol = (lane & 7) * 8;

  for (int kblk = 0; kblk < 12; ++kblk) {
    const int koff = kblk * 64;
#pragma unroll
    for (int i = 0; i < 4; ++i) {
      gload_lds16(A  + (size_t)(arowbase + i * 32 + srow) * 768 + koff + scol,
                  &As[(i * 32 + wave * 8) * 64]);
      gload_lds16(Bw + (size_t)(browbase + i * 32 + srow) * 768 + koff + scol,
                  &Bs[(i * 32 + wave * 8) * 64]);
    }
    __syncthreads();
#pragma unroll
    for (int ks = 0; ks < 2; ++ks) {
      short8 af[4], bf[4];
#pragma unroll
      for (int mi = 0; mi < 4; ++mi)
        af[mi] = *(const short8*)&As[(wm * 64 + mi * 16 + lq) * 64 + ks * 32 + grp * 8];
#pragma unroll
      for (int ni = 0; ni < 4; ++ni)
        bf[ni] = *(const short8*)&Bs[(wn * 64 + ni * 16 + lq) * 64 + ks * 32 + grp * 8];
#pragma unroll
      for (int mi = 0; mi < 4; ++mi)
#pragma unroll
        for (int ni = 0; ni < 4; ++ni)
          acc[mi][ni] = __builtin_amdgcn_mfma_f32_16x16x32_bf16(af[mi], bf[ni], acc[mi][ni], 0, 0, 0);
    }
    __syncthreads();
  }

#pragma unroll
  for (int mi = 0; mi < 4; ++mi) {
#pragma unroll
    for (int ni = 0; ni < 4; ++ni) {
      const int n = browbase + wn * 64 + ni * 16 + lq;
      const unsigned s = (unsigned)n / 768u;
      const int rem = n - (int)s * 768;
      const int hh = rem >> 6, d = rem & 63;
#pragma unroll
      for (int j = 0; j < 4; ++j) {
        const int m = arowbase + wm * 64 + mi * 16 + grp * 4 + j;
        if (m < MROWS) {
          const unsigned bb = (unsigned)m / 577u;
          const int t = m - (int)bb * 577;
          const unsigned short bv = f2bf(acc[mi][ni][j]);
          const size_t bh = (size_t)bb * H_ + hh;
          if (s == 0)      qb  [(bh * NPAD + t) * HD_ + d] = bv;
          else if (s == 1) kbuf[(bh * NPAD + t) * HD_ + d] = bv;
          else             vtb [(bh * HD_ + d) * NPAD + t] = bv;
        }
      }
    }
  }
}

// ---------------- Fused attention ----------------
// v7: counted-vmcnt pipelining. __syncthreads (full vmcnt0 drain each iter,
// lockstep) replaced by raw s_barrier + s_waitcnt vmcnt(4): per iteration the
// program order is stage(k+1) [4 gload_lds] -> prevload(k+1) [exactly 4 loads,
// unconditional via row-clamp so EVERY wave issues them] -> compute -> stores.
// In-order vmem retirement => vmcnt(4) ("all but newest 4 retired") always
// retires the stage; scores stores are newest so they FLOAT a full iteration
// across the barrier; prev/K/V prefetches get full-iteration cover. Iter 8
// syncs with vmcnt(0) once (makes loadPrev(9)'s ragged count irrelevant).
__global__ __launch_bounds__(256, 3) void attn_kernel(
    const unsigned short* __restrict__ qb,
    const unsigned short* __restrict__ kb,
    const unsigned short* __restrict__ vtb,
    const float* __restrict__ prev,
    float* __restrict__ scores_out,   // d_out + OUT0_ELTS
    unsigned short* __restrict__ ob)  // [MPAD][768] bf16
{
  const int qblk = blockIdx.x;   // 0..9
  const int bh   = blockIdx.y;   // 0..383
  const int tid  = threadIdx.x;
  const int wave = tid >> 6;
  const int lane = tid & 63;
  const int lq = lane & 15, grp = lane >> 4;

  const int b = bh / H_;
  const int h = bh - b * H_;

  const unsigned short* qp = qb  + (size_t)bh * NPAD * HD_;
  const unsigned short* kp = kb  + (size_t)bh * NPAD * HD_;
  const unsigned short* vp = vtb + (size_t)bh * HD_ * NPAD;

  const int qrow = qblk * 64 + wave * 16 + lq;
  const bool qvalid = (qrow < N_);

  // Row-clamped prev pointer: dead lanes/waves read row 576 (valid memory,
  // values discarded) so loadPrev ALWAYS issues exactly 4 load instructions
  // per wave — required for the vmcnt(4) count to be sound on every wave.
  const float* prevrow_c = prev + ((size_t)bh * N_ + (qvalid ? qrow : (N_ - 1))) * N_;
  float* srow_base = scores_out + (size_t)bh * N_ * N_;

  __shared__ __attribute__((aligned(16))) unsigned short ldsK[2][4096];
  __shared__ __attribute__((aligned(16))) unsigned short ldsV[2][4096];
  __shared__ __attribute__((aligned(16))) float sslab[4][16][68];

  short8 qf0, qf1;
  {
    const unsigned short* qr = qp + (size_t)qrow * HD_ + grp * 8;
    qf0 = *(const short8*)(qr);
    qf1 = *(const short8*)(qr + 32);
  }

  f32x4 oacc[4] = {};
  float lacc = 0.f;

  const int rhi = tid >> 3;                       // 0..31
  const int chk = (tid & 7) ^ (rhi & 7);
  auto stageKV = [&](int kblk, int bufi) {
    const int kbase = kblk * 64;
#pragma unroll
    for (int r = 0; r < 2; ++r) {
      gload_lds16(kp + (size_t)(kbase + r * 32 + rhi) * HD_ + chk * 8,
                  &ldsK[bufi][r * 2048 + wave * 512]);
      gload_lds16(vp + (size_t)(r * 32 + rhi) * NPAD + kbase + chk * 8,
                  &ldsV[bufi][r * 2048 + wave * 512]);
    }
  };

  auto loadPrev = [&](int kblk, float pv[16]) {
#pragma unroll
    for (int t = 0; t < 4; ++t) {
      const int kg0 = kblk * 64 + t * 16 + grp * 4;
      float tmp[4] = {0.f, 0.f, 0.f, 0.f};
      if (kg0 + 3 < N_) {
        __builtin_memcpy(tmp, prevrow_c + kg0, 16);   // rows only 4B-aligned
      } else {
#pragma unroll
        for (int e = 0; e < 4; ++e)
          if (kg0 + e < N_) tmp[e] = prevrow_c[kg0 + e];
      }
#pragma unroll
      for (int e = 0; e < 4; ++e) pv[t * 4 + e] = tmp[e];
    }
  };

  // swizzled fragment slots (ushort offsets within a row's 64 ushorts)
  const int sl0 = ((grp)     ^ (lq & 7)) * 8;
  const int sl1 = ((grp + 4) ^ (lq & 7)) * 8;

  float pv[16], pvn[16];
  stageKV(0, 0);
  asm volatile("" ::: "memory");
  loadPrev(0, pv);
  asm volatile("" ::: "memory");
  asm volatile("s_waitcnt vmcnt(4)" ::: "memory");   // stage(0) retired; prev floats
  __builtin_amdgcn_s_barrier();
  __builtin_amdgcn_sched_barrier(0);

#pragma unroll 1
  for (int kblk = 0; kblk < 10; ++kblk) {
    const int cur = kblk & 1;
    const int kbase = kblk * 64;

    // issue next-tile stage + next prev loads first (full-iteration cover)
    if (kblk < 9) {
      stageKV(kblk + 1, cur ^ 1);
      asm volatile("" ::: "memory");   // pin: loads below stay below the stage
      loadPrev(kblk + 1, pvn);
      asm volatile("" ::: "memory");   // pin: stores/compute stay below
    }

    // S^T = K @ Q^T from LDS (per lane: col=q=lq, row=k-in-tile=grp*4+reg)
    f32x4 sacc[4] = {};
#pragma unroll
    for (int t = 0; t < 4; ++t) {
      const int row = (t * 16 + lq) * 64;
      short8 a0 = *(const short8*)&ldsK[cur][row + sl0];
      short8 a1 = *(const short8*)&ldsK[cur][row + sl1];
      sacc[t] = __builtin_amdgcn_mfma_f32_16x16x32_bf16(a0, qf0, sacc[t], 0, 0, 0);
      sacc[t] = __builtin_amdgcn_mfma_f32_16x16x32_bf16(a1, qf1, sacc[t], 0, 0, 0);
    }

    // scale + prev, mask, write into this wave's slab in [q][k] layout
#pragma unroll
    for (int t = 0; t < 4; ++t) {
      const int kg0 = kbase + t * 16 + grp * 4;
      f32x4 sv;
#pragma unroll
      for (int r = 0; r < 4; ++r) {
        float sval = sacc[t][r] * SCALE + pv[t * 4 + r];
        if (kg0 + r >= N_) sval = -__builtin_inff();
        sv[r] = sval;
      }
      *(f32x4*)&sslab[wave][lq][t * 16 + grp * 4] = sv;
    }

    // P fragments: read own q-row back in [q][k] layout, exp, pack bf16
    short8 pf0, pf1;
    {
      const float* sr = &sslab[wave][lq][0];
      f32x4 x0 = *(const f32x4*)(sr + grp * 8);
      f32x4 x1 = *(const f32x4*)(sr + grp * 8 + 4);
      f32x4 x2 = *(const f32x4*)(sr + 32 + grp * 8);
      f32x4 x3 = *(const f32x4*)(sr + 32 + grp * 8 + 4);
      float e[16];
#pragma unroll
      for (int j = 0; j < 4; ++j) {
        e[j]      = __expf(x0[j]);
        e[4 + j]  = __expf(x1[j]);
        e[8 + j]  = __expf(x2[j]);
        e[12 + j] = __expf(x3[j]);
      }
#pragma unroll
      for (int j = 0; j < 16; ++j) lacc += e[j];
      ushort4v pa, pb2, pc, pd;
#pragma unroll
      for (int j = 0; j < 4; ++j) {
        ((unsigned short*)&pa)[j]  = f2bf(e[j]);
        ((unsigned short*)&pb2)[j] = f2bf(e[4 + j]);
        ((unsigned short*)&pc)[j]  = f2bf(e[8 + j]);
        ((unsigned short*)&pd)[j]  = f2bf(e[12 + j]);
      }
      union { struct { ushort4v a, b; } s; short8 v; } u0, u1;
      u0.s.a = pa; u0.s.b = pb2; pf0 = u0.v;
      u1.s.a = pc; u1.s.b = pd;  pf1 = u1.v;
    }

    // O^T += V^T @ P^T from LDS
#pragma unroll
    for (int dt = 0; dt < 4; ++dt) {
      const int row = (dt * 16 + lq) * 64;
      short8 v0 = *(const short8*)&ldsV[cur][row + sl0];
      short8 v1 = *(const short8*)&ldsV[cur][row + sl1];
      oacc[dt] = __builtin_amdgcn_mfma_f32_16x16x32_bf16(v0, pf0, oacc[dt], 0, 0, 0);
      oacc[dt] = __builtin_amdgcn_mfma_f32_16x16x32_bf16(v1, pf1, oacc[dt], 0, 0, 0);
    }

    // cooperative coalesced scores store (issued LAST = newest vmem ops =>
    // they float across the barrier into the next iteration)
#pragma unroll
    for (int q4 = 0; q4 < 4; ++q4) {
      const int row16 = q4 * 4 + (lane >> 4);
      const int qrow_s = qblk * 64 + wave * 16 + row16;
      const int col0 = (lane & 15) * 4;
      const int kg = kbase + col0;
      if (qrow_s < N_) {
        f32x4 vals = *(const f32x4*)&sslab[wave][row16][col0];
        float* dst = srow_base + (size_t)qrow_s * N_ + kg;
        if (kg + 3 < N_) {
          __builtin_memcpy(dst, &vals, 16);
        } else {
#pragma unroll
          for (int e2 = 0; e2 < 4; ++e2)
            if (kg + e2 < N_) dst[e2] = vals[e2];
        }
      }
    }

    if (kblk < 9) {
      // Retire stage(k+1) (all but newest 4; >=4 prevloads are younger), then
      // rendezvous. kblk==8: full drain once so iter 9's ragged prev count
      // doesn't matter.
      if (kblk == 8) asm volatile("s_waitcnt vmcnt(0)" ::: "memory");
      else           asm volatile("s_waitcnt vmcnt(4)" ::: "memory");
      __builtin_amdgcn_s_barrier();
      __builtin_amdgcn_sched_barrier(0);
#pragma unroll
      for (int i = 0; i < 16; ++i) pv[i] = pvn[i];
    }
  }

  // deferred l-reduce: lanes ^16, ^32 hold the other k-subsets of the same q-row
  lacc += __shfl_xor(lacc, 16, 64);
  lacc += __shfl_xor(lacc, 32, 64);

  if (qvalid) {
    const float rl = 1.0f / lacc;
    unsigned short* orow = ob + (size_t)(b * N_ + qrow) * C_ + h * HD_;
#pragma unroll
    for (int dt = 0; dt < 4; ++dt) {
      ushort4v ow;
      ow.x = f2bf(oacc[dt][0] * rl); ow.y = f2bf(oacc[dt][1] * rl);
      ow.z = f2bf(oacc[dt][2] * rl); ow.w = f2bf(oacc[dt][3] * rl);
      *(ushort4v*)(orow + dt * 16 + grp * 4) = ow;
    }
  }
}

// ---------------- Proj GEMM: out0[m,n] = sum_k ob[m,k]*Wproj[n,k] + bias[n] ----------------
__global__ __launch_bounds__(256) void gemm_proj(
    const unsigned short* __restrict__ A,    // ob [MPAD][768]
    const unsigned short* __restrict__ Bw,   // wprojb [768][768]
    const float* __restrict__ bias,
    float* __restrict__ out0)
{
  __shared__ unsigned short As[128 * 64];
  __shared__ unsigned short Bs[128 * 64];
  const int mt = blockIdx.x, nt = blockIdx.y;
  const int tid = threadIdx.x;
  const int wave = tid >> 6, lane = tid & 63;
  const int wm = wave >> 1, wn = wave & 1;
  const int lq = lane & 15, grp = lane >> 4;

  f32x4 acc[4][4] = {};

  const int arowbase = mt * 128;
  const int browbase = nt * 128;
  const int srow = wave * 8 + (lane >> 3);
  const int scol = (lane & 7) * 8;

  for (int kblk = 0; kblk < 12; ++kblk) {
    const int koff = kblk * 64;
#pragma unroll
    for (int i = 0; i < 4; ++i) {
      gload_lds16(A  + (size_t)(arowbase + i * 32 + srow) * 768 + koff + scol,
                  &As[(i * 32 + wave * 8) * 64]);
      gload_lds16(Bw + (size_t)(browbase + i * 32 + srow) * 768 + koff + scol,
                  &Bs[(i * 32 + wave * 8) * 64]);
    }
    __syncthreads();
#pragma unroll
    for (int ks = 0; ks < 2; ++ks) {
      short8 af[4], bf[4];
#pragma unroll
      for (int mi = 0; mi < 4; ++mi)
        af[mi] = *(const short8*)&As[(wm * 64 + mi * 16 + lq) * 64 + ks * 32 + grp * 8];
#pragma unroll
      for (int ni = 0; ni < 4; ++ni)
        bf[ni] = *(const short8*)&Bs[(wn * 64 + ni * 16 + lq) * 64 + ks * 32 + grp * 8];
#pragma unroll
      for (int mi = 0; mi < 4; ++mi)
#pragma unroll
        for (int ni = 0; ni < 4; ++ni)
          acc[mi][ni] = __builtin_amdgcn_mfma_f32_16x16x32_bf16(af[mi], bf[ni], acc[mi][ni], 0, 0, 0);
    }
    __syncthreads();
  }

#pragma unroll
  for (int ni = 0; ni < 4; ++ni) {
    const int n = browbase + wn * 64 + ni * 16 + lq;
    const float bv = bias[n];
#pragma unroll
    for (int mi = 0; mi < 4; ++mi) {
#pragma unroll
      for (int j = 0; j < 4; ++j) {
        const int m = arowbase + wm * 64 + mi * 16 + grp * 4 + j;
        if (m < MROWS) out0[(size_t)m * C_ + n] = acc[mi][ni][j] + bv;
      }
    }
  }
}

// ---------------- launch ----------------
extern "C" void kernel_launch(void* const* d_in, const int* in_sizes, int n_in,
                              void* d_out, int out_size, void* d_ws, size_t ws_size,
                              hipStream_t stream) {
  const float* x     = (const float*)d_in[0];
  const float* prev  = (const float*)d_in[1];
  const float* Wqkv  = (const float*)d_in[2];
  const float* Wproj = (const float*)d_in[3];
  const float* bproj = (const float*)d_in[4];
  float* out = (float*)d_out;

  char* ws = (char*)d_ws;
  size_t off = 0;
  auto alloc = [&](size_t bytes) {
    void* p = ws + off;
    off += (bytes + 255) & ~(size_t)255;
    return p;
  };
  unsigned short* xb     = (unsigned short*)alloc((size_t)MPAD * 768 * 2);
  unsigned short* wqkvb  = (unsigned short*)alloc((size_t)NQKV * 768 * 2);
  unsigned short* wprojb = (unsigned short*)alloc((size_t)768 * 768 * 2);
  unsigned short* qb     = (unsigned short*)alloc((size_t)B_ * H_ * NPAD * HD_ * 2);
  unsigned short* kbuf   = (unsigned short*)alloc((size_t)B_ * H_ * NPAD * HD_ * 2);
  unsigned short* vtb    = (unsigned short*)alloc((size_t)B_ * H_ * HD_ * NPAD * 2);
  unsigned short* ob     = (unsigned short*)alloc((size_t)MPAD * 768 * 2);
  (void)ob;

  // Only vtb's padding must be guaranteed finite: PV multiplies P=0 by pad V
  // columns, and 0 * NaN = NaN in MFMA. All other pad values are discarded
  // arithmetically (masked to -inf or dropped by m<MROWS / qvalid guards).
  hipMemsetAsync(vtb, 0, (size_t)B_ * H_ * HD_ * NPAD * 2, stream);

  {
    int n4 = (B_ * N_ * C_) / 4;
    cvt_f32_bf16<<<(n4 + 255) / 256, 256, 0, stream>>>(x, xb, n4);
    n4 = (NQKV * C_) / 4;
    cvt_f32_bf16<<<(n4 + 255) / 256, 256, 0, stream>>>(Wqkv, wqkvb, n4);
    n4 = (C_ * C_) / 4;
    cvt_f32_bf16<<<(n4 + 255) / 256, 256, 0, stream>>>(Wproj, wprojb, n4);
  }

  gemm_qkv<<<dim3(MPAD / 128, NQKV / 128), 256, 0, stream>>>(xb, wqkvb, qb, kbuf, vtb);

  attn_kernel<<<dim3(10, B_ * H_), 256, 0, stream>>>(qb, kbuf, vtb, prev,
                                                     out + OUT0_ELTS, ob);

  gemm_proj<<<dim3(MPAD / 128, C_ / 128), 256, 0, stream>>>(ob, wprojb, bproj, out);
}